// Round 3
// baseline (650.874 us; speedup 1.0000x reference)
//
#include <hip/hip_runtime.h>

// B=16384, F=40, D=32, fp32 throughout.
#define B_TOT    16384
#define FF       40
#define DD       32
#define NB       4            // batch elements per block (one wave each in phase 2)
#define NTHREADS 256          // 4 waves
#define HOP      36           // padded row stride for s_ho (floats)
#define HOB      (FF * HOP)   // per-b block in s_ho = 1440 floats

// LDS: s_ho = 23 KB. __launch_bounds__(256,6): <=84 VGPR -> 6 blocks/CU
// (138 KB LDS), 24 waves/CU. R1 at (256,4) gave 43% occupancy and 345 us,
// latency-bound (VALUBusy 26%, HBM 21%); this round: occupancy + 2x MLP.

__global__ __launch_bounds__(NTHREADS, 6)
void graphlayer_fused(const float* __restrict__ g,
                      const float* __restrict__ h,
                      const float* __restrict__ Win,
                      const float* __restrict__ Wout,
                      const float* __restrict__ bias,
                      float* __restrict__ out)
{
    __shared__ __attribute__((aligned(16))) float s_ho[NB * HOB];  // 5760 floats

    const int t  = threadIdx.x;
    const int b0 = blockIdx.x * NB;

    // ---- Phase 1: h_out[b][f][d] = sum_e Wout[f][d][e] * h[b][f][e] ----
    // unrolled x2 over f: both W-row loads (L1-missing, high latency) issue
    // up front; h loads follow; 2 independent dot chains per blx.
    {
        const int fh = t >> 7;          // 0..1 (f-half)
        const int d1 = (t >> 2) & 31;   // 0..31
        const int eq = t & 3;           // 0..3 (e-chunk of 8)
        for (int fi = 0; fi < 20; fi += 2) {
            const int fA = fh * 20 + fi;
            const int fB = fA + 1;
            const float4* wrA = (const float4*)(Wout + fA * (DD * DD) + d1 * DD + eq * 8);
            const float4* wrB = (const float4*)(Wout + fB * (DD * DD) + d1 * DD + eq * 8);
            float4 wa0 = wrA[0], wa1 = wrA[1];
            float4 wb0 = wrB[0], wb1 = wrB[1];
            float partA[NB], partB[NB];
            #pragma unroll
            for (int blx = 0; blx < NB; ++blx) {
                const float* hb = h + (size_t)(b0 + blx) * (FF * DD) + eq * 8;
                const float4* hrA = (const float4*)(hb + fA * DD);
                const float4* hrB = (const float4*)(hb + fB * DD);
                float4 ha0 = hrA[0], ha1 = hrA[1];
                float4 hb0 = hrB[0], hb1 = hrB[1];
                partA[blx] = wa0.x * ha0.x + wa0.y * ha0.y + wa0.z * ha0.z + wa0.w * ha0.w
                           + wa1.x * ha1.x + wa1.y * ha1.y + wa1.z * ha1.z + wa1.w * ha1.w;
                partB[blx] = wb0.x * hb0.x + wb0.y * hb0.y + wb0.z * hb0.z + wb0.w * hb0.w
                           + wb1.x * hb1.x + wb1.y * hb1.y + wb1.z * hb1.z + wb1.w * hb1.w;
            }
            #pragma unroll
            for (int blx = 0; blx < NB; ++blx) {
                float va = partA[blx];
                va += __shfl_xor(va, 1);
                va += __shfl_xor(va, 2);
                partA[blx] = va;
                float vb = partB[blx];
                vb += __shfl_xor(vb, 1);
                vb += __shfl_xor(vb, 2);
                partB[blx] = vb;
            }
            float resA = partA[0];
            resA = (eq == 1) ? partA[1] : resA;
            resA = (eq == 2) ? partA[2] : resA;
            resA = (eq == 3) ? partA[3] : resA;
            float resB = partB[0];
            resB = (eq == 1) ? partB[1] : resB;
            resB = (eq == 2) ? partB[2] : resB;
            resB = (eq == 3) ? partB[3] : resB;
            s_ho[eq * HOB + fA * HOP + d1] = resA;
            s_ho[eq * HOB + fB * HOP + d1] = resB;
        }
    }
    __syncthreads();

    // ---- Phase 2: aggr[b][f][d] = sum_gg g[b][f][gg] * h_out[b][gg][d] ----
    {
        const int w  = t >> 6;          // wave -> b
        const int l  = t & 63;
        const int dg = l >> 3;          // d-quad 0..7
        const int fg = l & 7;           // f mod 8

        const float* gb   = g + (size_t)(b0 + w) * (FF * FF);
        const float* shob = s_ho + w * HOB;

        float acc[5][4];
        #pragma unroll
        for (int i = 0; i < 5; ++i)
            #pragma unroll
            for (int j = 0; j < 4; ++j) acc[i][j] = 0.f;

        for (int gc = 0; gc < 10; ++gc) {
            const int gg = gc << 2;
            // issue the 5 global g loads first (long latency), then LDS reads
            float4 gv[5];
            #pragma unroll
            for (int i = 0; i < 5; ++i)
                gv[i] = *(const float4*)(gb + (fg + (i << 3)) * FF + gg);
            float4 hv0 = *(const float4*)(shob + (gg + 0) * HOP + dg * 4);
            float4 hv1 = *(const float4*)(shob + (gg + 1) * HOP + dg * 4);
            float4 hv2 = *(const float4*)(shob + (gg + 2) * HOP + dg * 4);
            float4 hv3 = *(const float4*)(shob + (gg + 3) * HOP + dg * 4);
            #pragma unroll
            for (int i = 0; i < 5; ++i) {
                acc[i][0] += gv[i].x * hv0.x + gv[i].y * hv1.x + gv[i].z * hv2.x + gv[i].w * hv3.x;
                acc[i][1] += gv[i].x * hv0.y + gv[i].y * hv1.y + gv[i].z * hv2.y + gv[i].w * hv3.y;
                acc[i][2] += gv[i].x * hv0.z + gv[i].y * hv1.z + gv[i].z * hv2.z + gv[i].w * hv3.z;
                acc[i][3] += gv[i].x * hv0.w + gv[i].y * hv1.w + gv[i].z * hv2.w + gv[i].w * hv3.w;
            }
        }
        __syncthreads();   // all phase-2 LDS reads done before overwrite
        #pragma unroll
        for (int i = 0; i < 5; ++i) {
            const int f = fg + (i << 3);
            *(float4*)(s_ho + w * HOB + f * HOP + dg * 4) =
                make_float4(acc[i][0], acc[i][1], acc[i][2], acc[i][3]);
        }
    }
    __syncthreads();

    // ---- Phase 3: a[b][f][d] = bias[d] + sum_e Win[f][d][e] * aggr[b][f][e] ----
    {
        const int fh = t >> 7;
        const int d1 = (t >> 2) & 31;
        const int eq = t & 3;
        const float biasv = bias[d1];
        for (int fi = 0; fi < 20; fi += 2) {
            const int fA = fh * 20 + fi;
            const int fB = fA + 1;
            const float4* wrA = (const float4*)(Win + fA * (DD * DD) + d1 * DD + eq * 8);
            const float4* wrB = (const float4*)(Win + fB * (DD * DD) + d1 * DD + eq * 8);
            float4 wa0 = wrA[0], wa1 = wrA[1];
            float4 wb0 = wrB[0], wb1 = wrB[1];
            float partA[NB], partB[NB];
            #pragma unroll
            for (int blx = 0; blx < NB; ++blx) {
                const float* ab = s_ho + blx * HOB + eq * 8;
                const float4* arA = (const float4*)(ab + fA * HOP);
                const float4* arB = (const float4*)(ab + fB * HOP);
                float4 aa0 = arA[0], aa1 = arA[1];
                float4 ab0 = arB[0], ab1 = arB[1];
                partA[blx] = wa0.x * aa0.x + wa0.y * aa0.y + wa0.z * aa0.z + wa0.w * aa0.w
                           + wa1.x * aa1.x + wa1.y * aa1.y + wa1.z * aa1.z + wa1.w * aa1.w;
                partB[blx] = wb0.x * ab0.x + wb0.y * ab0.y + wb0.z * ab0.z + wb0.w * ab0.w
                           + wb1.x * ab1.x + wb1.y * ab1.y + wb1.z * ab1.z + wb1.w * ab1.w;
            }
            #pragma unroll
            for (int blx = 0; blx < NB; ++blx) {
                float va = partA[blx];
                va += __shfl_xor(va, 1);
                va += __shfl_xor(va, 2);
                partA[blx] = va;
                float vb = partB[blx];
                vb += __shfl_xor(vb, 1);
                vb += __shfl_xor(vb, 2);
                partB[blx] = vb;
            }
            float resA = partA[0];
            resA = (eq == 1) ? partA[1] : resA;
            resA = (eq == 2) ? partA[2] : resA;
            resA = (eq == 3) ? partA[3] : resA;
            float resB = partB[0];
            resB = (eq == 1) ? partB[1] : resB;
            resB = (eq == 2) ? partB[2] : resB;
            resB = (eq == 3) ? partB[3] : resB;
            float* ob = out + (size_t)(b0 + eq) * (FF * DD) + d1;
            ob[fA * DD] = resA + biasv;
            ob[fB * DD] = resB + biasv;
        }
    }
}

extern "C" void kernel_launch(void* const* d_in, const int* in_sizes, int n_in,
                              void* d_out, int out_size, void* d_ws, size_t ws_size,
                              hipStream_t stream) {
    const float* g    = (const float*)d_in[0];
    const float* h    = (const float*)d_in[1];
    const float* Win  = (const float*)d_in[2];
    const float* Wout = (const float*)d_in[3];
    const float* bias = (const float*)d_in[4];
    float* out = (float*)d_out;

    dim3 grid(B_TOT / NB);
    dim3 block(NTHREADS);
    graphlayer_fused<<<grid, block, 0, stream>>>(g, h, Win, Wout, bias, out);
}

// Round 4
// 400.799 us; speedup vs baseline: 1.6239x; 1.6239x over previous
//
#include <hip/hip_runtime.h>

// B=16384, F=40, D=32, fp32. Three streaming kernels, no scratch:
//  K1: h_out[b,f,d] = sum_e Wout[f,d,e] h[b,f,e]            (h -> d_out)
//  K2: aggr[b,f,d]  = sum_g  g[b,f,g]  h_out[b,g,d]         (d_out in-place)
//  K3: a[b,f,d]     = sum_e Win[f,d,e] aggr[b,f,e] + bias   (d_out in-place)
// R0-R2 lesson: the fused 4-b block shape is latency-serialized regardless of
// occupancy (345 us at both 16% and 43% occ). R2 lesson: never VGPR-cap into
// spills (WRITE_SIZE 709 MB of scratch traffic).

#define B_TOT 16384
#define FF    40
#define DD    32

// ---- K1/K3: per-field DxD transform, one thread per (b,f) row --------------
// W address is wave-uniform (blockIdx only) -> scalar s_load path; h row is
// 128 B contiguous per thread; 1024 FMAs/thread back-to-back.
template<bool ADD_BIAS, bool IN_PLACE>
__global__ __launch_bounds__(256)
void field_transform(const float* __restrict__ W,     // [F][D][D]
                     const float* __restrict__ src,   // [B][F][D]
                     const float* __restrict__ bias,  // [D]
                     float* __restrict__ dst)         // [B][F][D]
{
    const int f = blockIdx.y;
    const int b = blockIdx.x * 256 + threadIdx.x;
    const float* wf = W + (size_t)f * (DD * DD);
    const float* srow = (IN_PLACE ? (const float*)dst : src)
                        + ((size_t)b * FF + f) * DD;

    float4 hr[8];
    #pragma unroll
    for (int j = 0; j < 8; ++j) hr[j] = ((const float4*)srow)[j];

    float acc[DD];
    #pragma unroll
    for (int d = 0; d < DD; ++d) {
        const float4* wrow = (const float4*)(wf + d * DD);  // uniform -> SGPR
        float s = 0.f;
        #pragma unroll
        for (int j = 0; j < 8; ++j) {
            float4 w = wrow[j];
            s += w.x * hr[j].x + w.y * hr[j].y + w.z * hr[j].z + w.w * hr[j].w;
        }
        if (ADD_BIAS) s += bias[d];                          // uniform -> SGPR
        acc[d] = s;
    }

    float* drow = dst + ((size_t)b * FF + f) * DD;
    #pragma unroll
    for (int j = 0; j < 8; ++j)
        ((float4*)drow)[j] = make_float4(acc[4*j+0], acc[4*j+1],
                                         acc[4*j+2], acc[4*j+3]);
}

// ---- K2: graph aggregation over fields, in-place on io ---------------------
// Block owns 4 batch elements. h_out staged to LDS (coalesced, conflict-free
// reads: dg spans all 32 banks, fg 8-way broadcast). g read direct from
// global (8-way dg-broadcast per instr). Writes after __syncthreads, only to
// this block's own 4-b slice -> in-place safe.
__global__ __launch_bounds__(256)
void graph_aggr(const float* __restrict__ g,   // [B][F][F]
                float* __restrict__ io)        // [B][F][D] h_out -> aggr
{
    __shared__ __attribute__((aligned(16))) float s_ho[4 * FF * DD]; // 20 KB
    const int t  = threadIdx.x;
    const int b0 = blockIdx.x * 4;

    // stage h_out for 4 b's (5120 floats = 1280 float4, coalesced)
    const float4* src = (const float4*)(io + (size_t)b0 * (FF * DD));
    #pragma unroll
    for (int k = 0; k < 5; ++k)
        ((float4*)s_ho)[t + k * 256] = src[t + k * 256];
    __syncthreads();

    const int w  = t >> 6;          // wave -> batch element
    const int l  = t & 63;
    const int dg = l >> 3;          // d-quad 0..7
    const int fg = l & 7;           // f mod 8

    const float* gb   = g + (size_t)(b0 + w) * (FF * FF);
    const float* shob = s_ho + w * (FF * DD);

    float acc[5][4];
    #pragma unroll
    for (int i = 0; i < 5; ++i)
        #pragma unroll
        for (int j = 0; j < 4; ++j) acc[i][j] = 0.f;

    for (int gc = 0; gc < 10; ++gc) {
        const int gg = gc << 2;
        float4 gv[5];
        #pragma unroll
        for (int i = 0; i < 5; ++i)
            gv[i] = *(const float4*)(gb + (fg + (i << 3)) * FF + gg);
        float4 hv0 = *(const float4*)(shob + (gg + 0) * DD + dg * 4);
        float4 hv1 = *(const float4*)(shob + (gg + 1) * DD + dg * 4);
        float4 hv2 = *(const float4*)(shob + (gg + 2) * DD + dg * 4);
        float4 hv3 = *(const float4*)(shob + (gg + 3) * DD + dg * 4);
        #pragma unroll
        for (int i = 0; i < 5; ++i) {
            acc[i][0] += gv[i].x * hv0.x + gv[i].y * hv1.x + gv[i].z * hv2.x + gv[i].w * hv3.x;
            acc[i][1] += gv[i].x * hv0.y + gv[i].y * hv1.y + gv[i].z * hv2.y + gv[i].w * hv3.y;
            acc[i][2] += gv[i].x * hv0.z + gv[i].y * hv1.z + gv[i].z * hv2.z + gv[i].w * hv3.z;
            acc[i][3] += gv[i].x * hv0.w + gv[i].y * hv1.w + gv[i].z * hv2.w + gv[i].w * hv3.w;
        }
    }

    #pragma unroll
    for (int i = 0; i < 5; ++i) {
        const int f = fg + (i << 3);
        *(float4*)(io + ((size_t)(b0 + w) * FF + f) * DD + dg * 4) =
            make_float4(acc[i][0], acc[i][1], acc[i][2], acc[i][3]);
    }
}

extern "C" void kernel_launch(void* const* d_in, const int* in_sizes, int n_in,
                              void* d_out, int out_size, void* d_ws, size_t ws_size,
                              hipStream_t stream) {
    const float* g    = (const float*)d_in[0];
    const float* h    = (const float*)d_in[1];
    const float* Win  = (const float*)d_in[2];
    const float* Wout = (const float*)d_in[3];
    const float* bias = (const float*)d_in[4];
    float* out = (float*)d_out;

    dim3 block(256);
    dim3 gridFT(B_TOT / 256, FF);      // 64 x 40
    dim3 gridAG(B_TOT / 4);            // 4096

    // K1: h_out -> d_out
    field_transform<false, false><<<gridFT, block, 0, stream>>>(Wout, h, bias, out);
    // K2: aggr, in place on d_out
    graph_aggr<<<gridAG, block, 0, stream>>>(g, out);
    // K3: final transform + bias, in place on d_out
    field_transform<true, true><<<gridFT, block, 0, stream>>>(Win, nullptr, bias, out);
}